// Round 1
// baseline (371.162 us; speedup 1.0000x reference)
//
#include <hip/hip_runtime.h>
#include <math.h>

#define I_N 64
#define Q_N 49
#define T_N 64
#define S_N 64
#define D_N 256
#define LAMBDA_SM 10.0f
#define SLOPE 0.1f

__device__ __forceinline__ float waveReduceSum64(float v) {
    v += __shfl_xor(v, 1);
    v += __shfl_xor(v, 2);
    v += __shfl_xor(v, 4);
    v += __shfl_xor(v, 8);
    v += __shfl_xor(v, 16);
    v += __shfl_xor(v, 32);
    return v;
}

// One block (256 threads) per row of D_N=256 elements: out = row / max(||row||, 1e-12)
__global__ void row_l2norm(const float* __restrict__ in, float* __restrict__ out, int nrows) {
    int row = blockIdx.x;
    if (row >= nrows) return;
    const float* p = in + (size_t)row * D_N;
    float* o = out + (size_t)row * D_N;
    int tid = threadIdx.x;
    float x = p[tid];
    float ss = x * x;
    __shared__ float wsum[4];
    float w = waveReduceSum64(ss);
    int wave = tid >> 6, lane = tid & 63;
    if (lane == 0) wsum[wave] = w;
    __syncthreads();
    float tot = wsum[0] + wsum[1] + wsum[2] + wsum[3];
    float inv = 1.0f / fmaxf(sqrtf(tot), 1e-12f);
    o[tid] = x * inv;
}

// norm only (no normalize): out[row] = ||row||
__global__ void row_norm_only(const float* __restrict__ in, float* __restrict__ out, int nrows) {
    int row = blockIdx.x;
    if (row >= nrows) return;
    const float* p = in + (size_t)row * D_N;
    int tid = threadIdx.x;
    float x = p[tid];
    float ss = x * x;
    __shared__ float wsum[4];
    float w = waveReduceSum64(ss);
    int wave = tid >> 6, lane = tid & 63;
    if (lane == 0) wsum[wave] = w;
    __syncthreads();
    if (tid == 0) {
        out[row] = sqrtf(wsum[0] + wsum[1] + wsum[2] + wsum[3]);
    }
}

#define LDS_STRIDE 65

__launch_bounds__(256, 1)
__global__ void i2t_kernel(const float* __restrict__ qn,     // [I,Q,D] normalized
                           const float* __restrict__ kn,     // [T,S,D] normalized
                           const float* __restrict__ tval,   // [T,S,D] raw text value
                           const float* __restrict__ vimg,   // [I,Q,D] raw img value
                           const float* __restrict__ vnorm,  // [I*Q] ||img value||
                           const int*   __restrict__ tlen,   // [T]
                           float* __restrict__ out)          // [I,T]
{
    __shared__ float As[64 * LDS_STRIDE];  // attn [s][q] (leaky applied)
    __shared__ float B1[64 * LDS_STRIDE];  // k-tile, later Ps[q][s]
    __shared__ float B2[64 * LDS_STRIDE];  // q-tile, later v-tile
    __shared__ float rinv[64];
    __shared__ float simq[64];

    const int t = blockIdx.x;
    const int i = blockIdx.y;
    const int tid = threadIdx.x;
    const int tx = tid & 15;   // phase1: q group;  phase3: dd group
    const int ty = tid >> 4;   // phase1: s group;  phase3: q group

    const float* knt = kn + (size_t)t * S_N * D_N;
    const float* qni = qn + (size_t)i * Q_N * D_N;

    // ---------------- Phase 1: attn[s][q] = sum_d kn[t,s,d]*qn[i,q,d] ----------------
    float acc[4][4];
#pragma unroll
    for (int a = 0; a < 4; ++a)
#pragma unroll
        for (int b = 0; b < 4; ++b) acc[a][b] = 0.0f;

    for (int d0 = 0; d0 < D_N; d0 += 64) {
#pragma unroll
        for (int r = 0; r < 16; ++r) {
            int idx = r * 256 + tid;       // 0..4095
            int s = idx >> 6, dd = idx & 63;
            B1[s * LDS_STRIDE + dd] = knt[s * D_N + d0 + dd];
            B2[s * LDS_STRIDE + dd] = (s < Q_N) ? qni[s * D_N + d0 + dd] : 0.0f;
        }
        __syncthreads();
#pragma unroll 4
        for (int dd = 0; dd < 64; ++dd) {
            float a[4], b[4];
#pragma unroll
            for (int j = 0; j < 4; ++j) a[j] = B1[(ty * 4 + j) * LDS_STRIDE + dd];
#pragma unroll
            for (int j = 0; j < 4; ++j) b[j] = B2[(tx * 4 + j) * LDS_STRIDE + dd];
#pragma unroll
            for (int sj = 0; sj < 4; ++sj)
#pragma unroll
                for (int qj = 0; qj < 4; ++qj) acc[sj][qj] += a[sj] * b[qj];
        }
        __syncthreads();
    }

    // LeakyReLU + store to As[s][q]
#pragma unroll
    for (int sj = 0; sj < 4; ++sj)
#pragma unroll
        for (int qj = 0; qj < 4; ++qj) {
            float v = acc[sj][qj];
            v = (v > 0.0f) ? v : SLOPE * v;
            As[(ty * 4 + sj) * LDS_STRIDE + (tx * 4 + qj)] = v;
        }
    __syncthreads();

    // ---------------- Phase 2a: per-s l2norm over q ----------------
    {
        int s = tid >> 2, part = tid & 3;
        float ss = 0.0f;
        for (int q = part; q < Q_N; q += 4) {
            float v = As[s * LDS_STRIDE + q];
            ss += v * v;
        }
        ss += __shfl_xor(ss, 1);
        ss += __shfl_xor(ss, 2);
        if (part == 0) rinv[s] = 1.0f / fmaxf(sqrtf(ss), 1e-12f);
    }
    __syncthreads();

    // ---------------- Phase 2b: masked softmax over s (per q) + focal ----------------
    const int len = tlen[t];
    const float thr = 1.0f / (float)len;
    {
        int q = tid >> 2, part = tid & 3;   // part handles s in [part*16, part*16+16)
        float logit[16];
        float m = -INFINITY;
#pragma unroll
        for (int k = 0; k < 16; ++k) {
            int s = part * 16 + k;
            float lg = (s < len) ? LAMBDA_SM * As[s * LDS_STRIDE + q] * rinv[s] : -INFINITY;
            logit[k] = lg;
            m = fmaxf(m, lg);
        }
        m = fmaxf(m, __shfl_xor(m, 1));
        m = fmaxf(m, __shfl_xor(m, 2));
        float p[16];
        float sum = 0.0f;
#pragma unroll
        for (int k = 0; k < 16; ++k) {
            int s = part * 16 + k;
            float e = (s < len) ? expf(logit[k] - m) : 0.0f;
            p[k] = e;
            sum += e;
        }
        sum += __shfl_xor(sum, 1);
        sum += __shfl_xor(sum, 2);
        float inv = 1.0f / sum;
        float sk = 0.0f;
#pragma unroll
        for (int k = 0; k < 16; ++k) {
            p[k] *= inv;
            if (p[k] > thr) sk += p[k];
        }
        sk += __shfl_xor(sk, 1);
        sk += __shfl_xor(sk, 2);
        float iv2 = 1.0f / sk;
#pragma unroll
        for (int k = 0; k < 16; ++k) {
            int s = part * 16 + k;
            B1[q * LDS_STRIDE + s] = (p[k] > thr) ? p[k] * iv2 : 0.0f;
        }
    }
    __syncthreads();

    // ---------------- Phase 3: wei[q][d] = sum_s Ps[q][s]*V[t,s,d]; fuse norms ----------------
    const float* tvt = tval + (size_t)t * S_N * D_N;
    const float* vi  = vimg + (size_t)i * Q_N * D_N;
    float sq[4] = {0, 0, 0, 0}, dv[4] = {0, 0, 0, 0};

    for (int d0 = 0; d0 < D_N; d0 += 64) {
#pragma unroll
        for (int r = 0; r < 16; ++r) {
            int idx = r * 256 + tid;
            int s = idx >> 6, dd = idx & 63;
            B2[s * LDS_STRIDE + dd] = tvt[s * D_N + d0 + dd];
        }
        __syncthreads();
        float w[4][4];
#pragma unroll
        for (int a = 0; a < 4; ++a)
#pragma unroll
            for (int b = 0; b < 4; ++b) w[a][b] = 0.0f;
#pragma unroll 4
        for (int s = 0; s < 64; ++s) {
            float a[4], b[4];
#pragma unroll
            for (int j = 0; j < 4; ++j) a[j] = B1[(ty * 4 + j) * LDS_STRIDE + s];
#pragma unroll
            for (int jj = 0; jj < 4; ++jj) b[jj] = B2[s * LDS_STRIDE + tx * 4 + jj];
#pragma unroll
            for (int j = 0; j < 4; ++j)
#pragma unroll
                for (int jj = 0; jj < 4; ++jj) w[j][jj] += a[j] * b[jj];
        }
#pragma unroll
        for (int j = 0; j < 4; ++j) {
            int q = ty * 4 + j;
            if (q < Q_N) {
#pragma unroll
                for (int jj = 0; jj < 4; ++jj) {
                    float vv = vi[q * D_N + d0 + tx * 4 + jj];
                    sq[j] += w[j][jj] * w[j][jj];
                    dv[j] += w[j][jj] * vv;
                }
            }
        }
        __syncthreads();
    }

    // reduce over tx (16 lanes, low 4 bits of lane id)
#pragma unroll
    for (int j = 0; j < 4; ++j) {
#pragma unroll
        for (int mask = 1; mask <= 8; mask <<= 1) {
            sq[j] += __shfl_xor(sq[j], mask);
            dv[j] += __shfl_xor(dv[j], mask);
        }
    }
    if (tx == 0) {
#pragma unroll
        for (int j = 0; j < 4; ++j) {
            int q = ty * 4 + j;
            if (q < Q_N) {
                float wn = sqrtf(sq[j]);
                float w12 = dv[j] / fmaxf(wn, 1e-12f);
                float wnn = wn / fmaxf(wn, 1e-12f);
                float vn = vnorm[i * Q_N + q];
                float denom = fmaxf(vn * wnn, 1e-8f);
                simq[q] = w12 / denom;
            }
        }
    }
    __syncthreads();
    if (tid < 64) {
        float v = (tid < Q_N) ? simq[tid] : 0.0f;
        v = waveReduceSum64(v);
        if (tid == 0) out[(size_t)i * T_N + t] = v * (1.0f / (float)Q_N);
    }
}

extern "C" void kernel_launch(void* const* d_in, const int* in_sizes, int n_in,
                              void* d_out, int out_size, void* d_ws, size_t ws_size,
                              hipStream_t stream) {
    const float* img_query = (const float*)d_in[0];  // [I,Q,D]
    const float* img_value = (const float*)d_in[1];  // [I,Q,D]
    const float* text_key  = (const float*)d_in[2];  // [T,S,D]
    const float* text_val  = (const float*)d_in[3];  // [T,S,D]
    const int*   text_len  = (const int*)d_in[4];    // [T]
    float* out = (float*)d_out;

    float* qn    = (float*)d_ws;                       // I*Q*D
    float* kn    = qn + (size_t)I_N * Q_N * D_N;       // T*S*D
    float* vnorm = kn + (size_t)T_N * S_N * D_N;       // I*Q

    row_l2norm<<<I_N * Q_N, 256, 0, stream>>>(img_query, qn, I_N * Q_N);
    row_l2norm<<<T_N * S_N, 256, 0, stream>>>(text_key, kn, T_N * S_N);
    row_norm_only<<<I_N * Q_N, 256, 0, stream>>>(img_value, vnorm, I_N * Q_N);

    dim3 grid(T_N, I_N);
    i2t_kernel<<<grid, 256, 0, stream>>>(qn, kn, text_val, img_value, vnorm, text_len, out);
}

// Round 2
// 201.285 us; speedup vs baseline: 1.8440x; 1.8440x over previous
//
#include <hip/hip_runtime.h>
#include <math.h>

#define I_N 64
#define Q_N 49
#define T_N 64
#define S_N 64
#define D_N 256

typedef __attribute__((ext_vector_type(8))) short short8;
typedef __attribute__((ext_vector_type(4))) float f32x4;
typedef unsigned short ushort_t;

__device__ __forceinline__ float waveReduceSum64(float v) {
    v += __shfl_xor(v, 1);
    v += __shfl_xor(v, 2);
    v += __shfl_xor(v, 4);
    v += __shfl_xor(v, 8);
    v += __shfl_xor(v, 16);
    v += __shfl_xor(v, 32);
    return v;
}

// RNE float -> bf16 bits (no NaN handling needed; inputs are finite)
__device__ __forceinline__ ushort_t f2bf(float x) {
    unsigned u = __builtin_bit_cast(unsigned, x);
    unsigned r = (u + 0x7fffu + ((u >> 16) & 1u)) >> 16;
    return (ushort_t)r;
}
__device__ __forceinline__ float bf2f(ushort_t h) {
    unsigned u = ((unsigned)h) << 16;
    return __builtin_bit_cast(float, u);
}
__device__ __forceinline__ void split_bf16(float x, ushort_t& h, ushort_t& l) {
    h = f2bf(x);
    l = f2bf(x - bf2f(h));
}

// ---------- prep: normalize img query rows (pad q>=49 with zeros), split to bf16 hi/lo,
// ---------- and compute ||img_value|| per (i,q). grid = I_N*64, block = 256.
__global__ void prep_img(const float* __restrict__ q_in, const float* __restrict__ v_in,
                         ushort_t* __restrict__ qh, ushort_t* __restrict__ ql,
                         float* __restrict__ vnorm) {
    int row = blockIdx.x;             // i*64 + q
    int i = row >> 6, q = row & 63;
    int tid = threadIdx.x;
    float x = 0.0f, vv = 0.0f;
    if (q < Q_N) {
        size_t base = ((size_t)i * Q_N + q) * D_N + tid;
        x = q_in[base];
        vv = v_in[base];
    }
    __shared__ float ws[8];
    float s1 = waveReduceSum64(x * x);
    float s2 = waveReduceSum64(vv * vv);
    int wv = tid >> 6, ln = tid & 63;
    if (ln == 0) { ws[wv] = s1; ws[4 + wv] = s2; }
    __syncthreads();
    float n1 = sqrtf(ws[0] + ws[1] + ws[2] + ws[3]);
    float n2 = sqrtf(ws[4] + ws[5] + ws[6] + ws[7]);
    float xn = x / fmaxf(n1, 1e-12f);
    ushort_t h, l;
    split_bf16(xn, h, l);
    qh[(size_t)row * D_N + tid] = h;
    ql[(size_t)row * D_N + tid] = l;
    if (tid == 0) vnorm[row] = n2;    // 0 for padded rows
}

// ---------- prep: normalize text key rows, split. grid = T_N*64, block = 256.
__global__ void prep_txt(const float* __restrict__ k_in,
                         ushort_t* __restrict__ kh, ushort_t* __restrict__ kl) {
    int row = blockIdx.x;             // t*64 + s
    int tid = threadIdx.x;
    float x = k_in[(size_t)row * D_N + tid];
    __shared__ float ws[4];
    float s1 = waveReduceSum64(x * x);
    int wv = tid >> 6, ln = tid & 63;
    if (ln == 0) ws[wv] = s1;
    __syncthreads();
    float n1 = sqrtf(ws[0] + ws[1] + ws[2] + ws[3]);
    float xn = x / fmaxf(n1, 1e-12f);
    ushort_t h, l;
    split_bf16(xn, h, l);
    kh[(size_t)row * D_N + tid] = h;
    kl[(size_t)row * D_N + tid] = l;
}

// ---------- prep: transpose text value to [T][D][S], split. grid = T_N, block = 256.
__global__ void prep_vt(const float* __restrict__ tv,
                        ushort_t* __restrict__ vth, ushort_t* __restrict__ vtl) {
    int t = blockIdx.x;
    int tid = threadIdx.x;
    const float* src = tv + ((size_t)t << 14);       // t*64*256
    ushort_t* dh = vth + ((size_t)t << 14);
    ushort_t* dl = vtl + ((size_t)t << 14);
    for (int kk = 0; kk < 64; ++kk) {
        int o = kk * 256 + tid;       // output index d*64+s
        int d = o >> 6, s = o & 63;
        float x = src[s * D_N + d];
        ushort_t h, l;
        split_bf16(x, h, l);
        dh[o] = h;
        dl[o] = l;
    }
}

// ---------- main: one block per (t,i) ----------
__launch_bounds__(256, 3)
__global__ void i2t_mfma(const ushort_t* __restrict__ qh, const ushort_t* __restrict__ ql,
                         const ushort_t* __restrict__ kh, const ushort_t* __restrict__ kl,
                         const ushort_t* __restrict__ vth, const ushort_t* __restrict__ vtl,
                         const float* __restrict__ vimg,   // [I][49][256] raw
                         const float* __restrict__ vnorm,  // [I][64]
                         const int* __restrict__ tlen,
                         float* __restrict__ out)          // [I][T]
{
    __shared__ float As[64 * 65];                       // attn [s][q], fp32, 16.6 KB
    __shared__ __align__(16) ushort_t Ph[64 * 64];      // P hi, swizzled 128B rows, 8 KB
    __shared__ __align__(16) ushort_t Pl[64 * 64];      // P lo, 8 KB
    __shared__ float rinv[64];
    __shared__ float wsq[4][64], wdv[4][64];

    const int t = blockIdx.x;
    const int i = blockIdx.y;
    const int tid = threadIdx.x;
    const int lane = tid & 63;
    const int w = tid >> 6;        // wave 0..3
    const int lr = lane & 15;      // fragment row/col index
    const int lk = lane >> 4;      // fragment k-group (0..3)

    // ================= Phase 1: attn[s][q] = kn[t] . qn[i]^T  (split-bf16 MFMA) =========
    {
        const int m0 = (w >> 1) * 32;   // s-base of this wave
        const int n0 = (w & 1) * 32;    // q-base
        const ushort_t* khT = kh + ((size_t)t << 14);
        const ushort_t* klT = kl + ((size_t)t << 14);
        const ushort_t* qhI = qh + ((size_t)i << 14);
        const ushort_t* qlI = ql + ((size_t)i << 14);

        f32x4 acc[2][2];
#pragma unroll
        for (int a = 0; a < 2; ++a)
#pragma unroll
            for (int b = 0; b < 2; ++b) acc[a][b] = (f32x4){0.f, 0.f, 0.f, 0.f};

#pragma unroll 4
        for (int k0 = 0; k0 < 256; k0 += 32) {
            short8 aH[2], aL[2], bH[2], bL[2];
            const int dd = k0 + lk * 8;
#pragma unroll
            for (int mi = 0; mi < 2; ++mi) {
                int s = m0 + mi * 16 + lr;
                aH[mi] = *(const short8*)(khT + s * D_N + dd);
                aL[mi] = *(const short8*)(klT + s * D_N + dd);
            }
#pragma unroll
            for (int ni = 0; ni < 2; ++ni) {
                int q = n0 + ni * 16 + lr;
                bH[ni] = *(const short8*)(qhI + q * D_N + dd);
                bL[ni] = *(const short8*)(qlI + q * D_N + dd);
            }
#pragma unroll
            for (int mi = 0; mi < 2; ++mi)
#pragma unroll
                for (int ni = 0; ni < 2; ++ni) {
                    acc[mi][ni] = __builtin_amdgcn_mfma_f32_16x16x32_bf16(aH[mi], bH[ni], acc[mi][ni], 0, 0, 0);
                    acc[mi][ni] = __builtin_amdgcn_mfma_f32_16x16x32_bf16(aH[mi], bL[ni], acc[mi][ni], 0, 0, 0);
                    acc[mi][ni] = __builtin_amdgcn_mfma_f32_16x16x32_bf16(aL[mi], bH[ni], acc[mi][ni], 0, 0, 0);
                }
        }
        // LeakyReLU + scatter to As[s][q]
#pragma unroll
        for (int mi = 0; mi < 2; ++mi)
#pragma unroll
            for (int ni = 0; ni < 2; ++ni)
#pragma unroll
                for (int r = 0; r < 4; ++r) {
                    int s = m0 + mi * 16 + lk * 4 + r;
                    int q = n0 + ni * 16 + lr;
                    float v = acc[mi][ni][r];
                    v = (v > 0.0f) ? v : 0.1f * v;
                    As[s * 65 + q] = v;
                }
    }
    __syncthreads();

    // ================= Phase 2a: per-s l2norm over q =================
    {
        int s = tid >> 2, part = tid & 3;
        float ss = 0.0f;
        for (int q = part; q < 64; q += 4) {
            float v = As[s * 65 + q];
            ss += v * v;
        }
        ss += __shfl_xor(ss, 1);
        ss += __shfl_xor(ss, 2);
        if (part == 0) rinv[s] = 1.0f / fmaxf(sqrtf(ss), 1e-12f);
    }
    __syncthreads();

    // ================= Phase 2b: masked softmax over s + focal, write P hi/lo =========
    const int len = tlen[t];
    {
        const float thr = 1.0f / (float)len;
        int q = tid >> 2, part = tid & 3;
        float logit[16];
        float m = -INFINITY;
#pragma unroll
        for (int k = 0; k < 16; ++k) {
            int s = part * 16 + k;
            float lg = (s < len) ? 10.0f * As[s * 65 + q] * rinv[s] : -INFINITY;
            logit[k] = lg;
            m = fmaxf(m, lg);
        }
        m = fmaxf(m, __shfl_xor(m, 1));
        m = fmaxf(m, __shfl_xor(m, 2));
        float p[16];
        float sum = 0.0f;
#pragma unroll
        for (int k = 0; k < 16; ++k) {
            int s = part * 16 + k;
            float e = (s < len) ? __expf(logit[k] - m) : 0.0f;
            p[k] = e;
            sum += e;
        }
        sum += __shfl_xor(sum, 1);
        sum += __shfl_xor(sum, 2);
        float inv = 1.0f / sum;
        float sk = 0.0f;
#pragma unroll
        for (int k = 0; k < 16; ++k) {
            p[k] *= inv;
            if (p[k] > thr) sk += p[k];
        }
        sk += __shfl_xor(sk, 1);
        sk += __shfl_xor(sk, 2);
        float iv2 = 1.0f / sk;

        ushort_t hh[16], ll[16];
#pragma unroll
        for (int k = 0; k < 16; ++k) {
            float pv = (p[k] > thr) ? p[k] * iv2 : 0.0f;
            if (q >= Q_N) pv = 0.0f;   // padded query rows -> zero weights
            split_bf16(pv, hh[k], ll[k]);
        }
        // swizzled 16B-chunk writes: chunk c of row q lives at (c ^ (q&7))
        int c0 = (2 * part) ^ (q & 7);
        int c1 = (2 * part + 1) ^ (q & 7);
        char* baseH = (char*)Ph + q * 128;
        char* baseL = (char*)Pl + q * 128;
        short8 v0, v1;
#pragma unroll
        for (int k = 0; k < 8; ++k) { v0[k] = (short)hh[k]; v1[k] = (short)hh[k + 8]; }
        *(short8*)(baseH + (c0 << 4)) = v0;
        *(short8*)(baseH + (c1 << 4)) = v1;
#pragma unroll
        for (int k = 0; k < 8; ++k) { v0[k] = (short)ll[k]; v1[k] = (short)ll[k + 8]; }
        *(short8*)(baseL + (c0 << 4)) = v0;
        *(short8*)(baseL + (c1 << 4)) = v1;
    }
    __syncthreads();

    // ================= Phase 3: wei[q][d] = P[q][s] * Vt[d][s]  (split-bf16 MFMA) ======
    f32x4 acc2[4][4];
#pragma unroll
    for (int a = 0; a < 4; ++a)
#pragma unroll
        for (int b = 0; b < 4; ++b) acc2[a][b] = (f32x4){0.f, 0.f, 0.f, 0.f};
    {
        const ushort_t* vhT = vth + ((size_t)t << 14);
        const ushort_t* vlT = vtl + ((size_t)t << 14);
#pragma unroll
        for (int k0 = 0; k0 < 64; k0 += 32) {
            short8 pah[4], pal[4];
#pragma unroll
            for (int mi = 0; mi < 4; ++mi) {
                int q = mi * 16 + lr;
                int c = (k0 >> 3) + lk;
                int off = q * 128 + ((c ^ (q & 7)) << 4);
                pah[mi] = *(const short8*)((const char*)Ph + off);
                pal[mi] = *(const short8*)((const char*)Pl + off);
            }
#pragma unroll
            for (int ni = 0; ni < 4; ++ni) {
                int d = w * 64 + ni * 16 + lr;
                int go = d * 64 + k0 + lk * 8;
                short8 bh = *(const short8*)(vhT + go);
                short8 bl = *(const short8*)(vlT + go);
#pragma unroll
                for (int mi = 0; mi < 4; ++mi) {
                    acc2[mi][ni] = __builtin_amdgcn_mfma_f32_16x16x32_bf16(pah[mi], bh, acc2[mi][ni], 0, 0, 0);
                    acc2[mi][ni] = __builtin_amdgcn_mfma_f32_16x16x32_bf16(pal[mi], bh, acc2[mi][ni], 0, 0, 0);
                    acc2[mi][ni] = __builtin_amdgcn_mfma_f32_16x16x32_bf16(pah[mi], bl, acc2[mi][ni], 0, 0, 0);
                }
            }
        }
    }

    // ================= Epilogue: fused ||wei|| and wei.v, reduce over d =================
    {
        const float* vI = vimg + (size_t)i * Q_N * D_N;
#pragma unroll
        for (int mi = 0; mi < 4; ++mi)
#pragma unroll
            for (int r = 0; r < 4; ++r) {
                int q = mi * 16 + lk * 4 + r;
                float s2 = 0.0f, dv = 0.0f;
#pragma unroll
                for (int ni = 0; ni < 4; ++ni) {
                    int d = w * 64 + ni * 16 + lr;
                    float wv = acc2[mi][ni][r];
                    float vv = (q < Q_N) ? vI[q * D_N + d] : 0.0f;
                    s2 += wv * wv;
                    dv += wv * vv;
                }
#pragma unroll
                for (int mask = 1; mask <= 8; mask <<= 1) {
                    s2 += __shfl_xor(s2, mask);
                    dv += __shfl_xor(dv, mask);
                }
                if (lr == 0) { wsq[w][q] = s2; wdv[w][q] = dv; }
            }
    }
    __syncthreads();
    if (tid < 64) {
        int q = tid;
        float s2 = wsq[0][q] + wsq[1][q] + wsq[2][q] + wsq[3][q];
        float dv = wdv[0][q] + wdv[1][q] + wdv[2][q] + wdv[3][q];
        float sim = 0.0f;
        if (q < Q_N) {
            float wn = sqrtf(s2);
            float w12 = dv / fmaxf(wn, 1e-12f);
            float wnn = wn / fmaxf(wn, 1e-12f);
            float denom = fmaxf(vnorm[i * 64 + q] * wnn, 1e-8f);
            sim = w12 / denom;
        }
        sim = waveReduceSum64(sim);
        if (tid == 0) out[(size_t)i * T_N + t] = sim * (1.0f / (float)Q_N);
    }
}

extern "C" void kernel_launch(void* const* d_in, const int* in_sizes, int n_in,
                              void* d_out, int out_size, void* d_ws, size_t ws_size,
                              hipStream_t stream) {
    const float* img_query = (const float*)d_in[0];  // [I,49,D]
    const float* img_value = (const float*)d_in[1];  // [I,49,D]
    const float* text_key  = (const float*)d_in[2];  // [T,64,D]
    const float* text_val  = (const float*)d_in[3];  // [T,64,D]
    const int*   text_len  = (const int*)d_in[4];    // [T]
    float* out = (float*)d_out;

    const size_t NPAD = (size_t)64 * 64 * 256;       // 1,048,576 elements
    ushort_t* qh  = (ushort_t*)d_ws;
    ushort_t* ql  = qh + NPAD;
    ushort_t* kh  = ql + NPAD;
    ushort_t* kl  = kh + NPAD;
    ushort_t* vth = kl + NPAD;
    ushort_t* vtl = vth + NPAD;
    float* vnorm  = (float*)(vtl + NPAD);            // [I*64]

    prep_img<<<I_N * 64, 256, 0, stream>>>(img_query, img_value, qh, ql, vnorm);
    prep_txt<<<T_N * 64, 256, 0, stream>>>(text_key, kh, kl);
    prep_vt<<<T_N, 256, 0, stream>>>(text_val, vth, vtl);

    dim3 grid(T_N, I_N);
    i2t_mfma<<<grid, 256, 0, stream>>>(qh, ql, kh, kl, vth, vtl,
                                       img_value, vnorm, text_len, out);
}